// Round 10
// baseline (116.646 us; speedup 1.0000x reference)
//
#include <hip/hip_runtime.h>

// Problem constants: B=4, S=512, H=256
#define Bn 4
#define Sn 512
#define Hn 256

#define CC   2.8853900817779268f   // 2*log2(e)
#define L2E  1.4426950408889634f

typedef __attribute__((ext_vector_type(4))) float f32x4;
typedef __attribute__((ext_vector_type(8))) short short8;

__device__ __forceinline__ unsigned short bf16rn(float f) {
    unsigned int u = __float_as_uint(f);
    u += 0x7fffu + ((u >> 16) & 1u);
    return (unsigned short)(u >> 16);
}
__device__ __forceinline__ float bf16tof(unsigned short b) {
    return __uint_as_float(((unsigned int)b) << 16);
}

// ---------------------------------------------------------------------------
// gemm (kept verbatim): R16 structure + (0,2,1,3) within-group layout
// permutation in Egt/Egp4/wa2 (proven bit-identical at the consumer).
// ---------------------------------------------------------------------------
__global__ __launch_bounds__(512, 4) void gemm_kernel(
    const float* __restrict__ h,  const float* __restrict__ Wt,
    const float* __restrict__ Wp, const float* __restrict__ Wa,
    const float* __restrict__ ba, const float* __restrict__ bh,
    float* __restrict__ Egt, float* __restrict__ Egp4,
    float* __restrict__ wa2, float* __restrict__ cst)
{
    // A1@0 A2@8704 (32x136 shorts) B1@17408 B2@34816 (64x136 shorts)
    // tile@52224 (32x68 f32; reused as ct) red4@60928
    __shared__ char lds[60944];
    unsigned short* A1 = (unsigned short*)lds;
    unsigned short* A2 = (unsigned short*)(lds + 8704);
    unsigned short* B1 = (unsigned short*)(lds + 17408);
    unsigned short* B2 = (unsigned short*)(lds + 34816);
    float* tile = (float*)(lds + 52224);
    float* red4 = (float*)(lds + 60928);

    const int tid = threadIdx.x;            // 0..511
    const int mb  = blockIdx.x >> 3;        // 0..63 (32-row m-tiles)
    const int nb  = blockIdx.x & 7;
    const int m0  = mb * 32;
    const bool isT = (nb < 4);
    const int n0  = (isT ? nb : nb - 4) * 64;
    const float* __restrict__ W = isT ? Wt : Wp;

    if (blockIdx.x == 0) {
        if (tid < 256) {
            float wv = Wa[tid];
#pragma unroll
            for (int off = 32; off >= 1; off >>= 1) wv += __shfl_xor(wv, off, 64);
            if ((tid & 63) == 0) red4[tid >> 6] = wv;
        }
        __syncthreads();
        if (tid < 256) {
            // permuted within group of 4: mem pos p holds orig j = {0,2,1,3}[p]
            const int p   = tid & 3;
            const int src = (tid & ~3) | (((p << 1) | (p >> 1)) & 3);
            wa2[tid] = -2.0f * Wa[src];
        }
        if (tid == 0)
            cst[0] = -L2E * ((red4[0] + red4[1] + red4[2] + red4[3]) + ba[0]);
    }

    const int w    = tid >> 6;              // 0..7
    const int w2   = w & 3;                 // n-quadrant
    const int mh   = w >> 2;                // m-half
    const int lane = tid & 63;
    const int quad = lane >> 4;
    const int l15  = lane & 15;

    f32x4 acc = (f32x4){0.f, 0.f, 0.f, 0.f};

    for (int kh2 = 0; kh2 < 2; kh2++) {
        const int K0 = kh2 << 7;
        __syncthreads();

        {
            const int row = tid >> 4;
            const int seg = (tid & 15) * 8;
            const float* __restrict__ src = h + (m0 + row) * Hn + K0 + seg;
            unsigned int* d1 = (unsigned int*)A1 + row * 68 + (seg >> 1);
            unsigned int* d2 = (unsigned int*)A2 + row * 68 + (seg >> 1);
#pragma unroll
            for (int i = 0; i < 2; i++) {
                const float4 v = ((const float4*)src)[i];
                const float f[4] = {v.x, v.y, v.z, v.w};
                unsigned short b1[4], b2[4];
#pragma unroll
                for (int j = 0; j < 4; j++) {
                    b1[j] = bf16rn(f[j]);
                    b2[j] = bf16rn(f[j] - bf16tof(b1[j]));
                }
                d1[2 * i]     = (unsigned)b1[0] | ((unsigned)b1[1] << 16);
                d1[2 * i + 1] = (unsigned)b1[2] | ((unsigned)b1[3] << 16);
                d2[2 * i]     = (unsigned)b2[0] | ((unsigned)b2[1] << 16);
                d2[2 * i + 1] = (unsigned)b2[2] | ((unsigned)b2[3] << 16);
            }
        }

        for (int kt = 0; kt < 4; kt++) {
            const int koff = K0 + kt * 32;
            if (kt) __syncthreads();
            {
                const int kr = tid >> 4;
                const int nq = tid & 15;
                *(float4*)&tile[kr * 68 + nq * 4] =
                    *(const float4*)&W[(koff + kr) * Hn + n0 + nq * 4];
            }
            __syncthreads();
            {
                const int n  = tid >> 3;
                const int p0 = (tid & 7) * 2;
                const float f0 = tile[(2 * p0    ) * 68 + n];
                const float f1 = tile[(2 * p0 + 1) * 68 + n];
                const float f2 = tile[(2 * p0 + 2) * 68 + n];
                const float f3 = tile[(2 * p0 + 3) * 68 + n];
                const unsigned short a0 = bf16rn(f0), a1 = bf16rn(f1);
                const unsigned short a2 = bf16rn(f2), a3 = bf16rn(f3);
                const unsigned short c0 = bf16rn(f0 - bf16tof(a0));
                const unsigned short c1 = bf16rn(f1 - bf16tof(a1));
                const unsigned short c2 = bf16rn(f2 - bf16tof(a2));
                const unsigned short c3 = bf16rn(f3 - bf16tof(a3));
                unsigned int* o1 = (unsigned int*)B1 + n * 68 + kt * 16 + p0;
                unsigned int* o2 = (unsigned int*)B2 + n * 68 + kt * 16 + p0;
                o1[0] = (unsigned)a0 | ((unsigned)a1 << 16);
                o1[1] = (unsigned)a2 | ((unsigned)a3 << 16);
                o2[0] = (unsigned)c0 | ((unsigned)c1 << 16);
                o2[1] = (unsigned)c2 | ((unsigned)c3 << 16);
            }
        }
        __syncthreads();

#pragma unroll
        for (int ks = 0; ks < 128; ks += 32) {
            const int bof = (w2 * 16 + l15) * 136 + ks + quad * 8;
            const short8 b1 = *(const short8*)(B1 + bof);
            const short8 b2 = *(const short8*)(B2 + bof);
            const int aof = (mh * 16 + l15) * 136 + ks + quad * 8;
            const short8 a1 = *(const short8*)(A1 + aof);
            const short8 a2 = *(const short8*)(A2 + aof);
            acc = __builtin_amdgcn_mfma_f32_16x16x32_bf16(a1, b1, acc, 0, 0, 0);
            acc = __builtin_amdgcn_mfma_f32_16x16x32_bf16(a1, b2, acc, 0, 0, 0);
            acc = __builtin_amdgcn_mfma_f32_16x16x32_bf16(a2, b1, acc, 0, 0, 0);
        }
    }

    float* ct = tile;
#pragma unroll
    for (int r = 0; r < 4; r++)
        ct[(mh * 16 + quad * 4 + r) * 68 + w2 * 16 + l15] = acc[r];
    __syncthreads();

    const int b  = m0 >> 9;
    const int s0 = m0 & 511;
    if (isT) {
        const int n0g = nb * 64;
        const int mr = tid >> 4, nq = tid & 15;
        const float4 c  = *(const float4*)&ct[mr * 68 + nq * 4];
        const float4 bv = *(const float4*)&bh[n0g + nq * 4];
        // permuted store: mem (x,y,z,w) <- orig (0,2,1,3)
        float4 o;
        o.x = __builtin_amdgcn_exp2f((c.x + bv.x) * CC);
        o.y = __builtin_amdgcn_exp2f((c.z + bv.z) * CC);
        o.z = __builtin_amdgcn_exp2f((c.y + bv.y) * CC);
        o.w = __builtin_amdgcn_exp2f((c.w + bv.w) * CC);
        *(float4*)&Egt[(m0 + mr) * Hn + n0g + nq * 4] = o;
    } else {
        const int kq0 = (nb - 4) * 16;
        const int mr = tid & 31, nq = tid >> 5;
        const float4 c = *(const float4*)&ct[mr * 68 + nq * 4];
        // permuted store: mem (x,y,z,w) <- orig (0,2,1,3)
        float4 o;
        o.x = __builtin_amdgcn_exp2f(c.x * CC);
        o.y = __builtin_amdgcn_exp2f(c.z * CC);
        o.z = __builtin_amdgcn_exp2f(c.y * CC);
        o.w = __builtin_amdgcn_exp2f(c.w * CC);
        *(float4*)&Egp4[b * 131072 + (kq0 + nq) * 2048 + (s0 + mr) * 4] = o;
    }
}

// ---------------------------------------------------------------------------
// attn R25: R23 structure (best: 40.6us) + pairwise rational fusion.
// R24 (SMEM->LDS) regressed 40.6->45.0 (+49K bank conflicts): SMEM wasn't
// the stall. R22==R23 under 2x occupancy: not wave-starvation either. The
// unpriced issue class: v_rcp_f32 is transcendental (~8-16cy/wave vs 2 for
// fma); phase 1 issues 4 rcp/kk. Fusion: nA/dA + nB/dB =
// (nA*dB + nB*dA)/(dA*dB) exactly -> 1 rcp per PAIR of k-groups (256->128
// rcp/thread), +3 fast ops, acc-fma halved. Loop keeps R23's exact
// rotation/prefetch skeleton, manually unrolled x2 (same codegen shape);
// only the combine differs. dA*dB = 8-term d-product, realistic max well
// inside fp32 range. absmax may shift a few ulp (6.7x headroom).
// ---------------------------------------------------------------------------
__global__ __launch_bounds__(512, 8) void attn_kernel(
    const float* __restrict__ hsrc, const float* __restrict__ Egt,
    const float* __restrict__ Egp4, const float* __restrict__ wa2,
    const float* __restrict__ cst,
    float* __restrict__ out, float* __restrict__ out_attn)
{
    __shared__ float  attn_l[4 * 512];     // 8 KB
    __shared__ float  red[32];
    __shared__ float4 part[4 * 4 * 64];    // 16 KB, two-stage q reduction

    const int tid = threadIdx.x;           // 0..511
    const int b   = blockIdx.x & 3;
    const int t0  = (blockIdx.x >> 2) << 2;

    const float* __restrict__ egt = Egt + (b * Sn + t0) * Hn;   // block-uniform
    const float4* __restrict__ ep = (const float4*)(Egp4 + b * (Hn * Sn));

    float acc0 = 0.f, acc1 = 0.f, acc2 = 0.f, acc3 = 0.f;

    float4 w4c  = *(const float4*)&wa2[0];
    float4 eg0c = *(const float4*)&egt[0 * Hn];
    float4 eg1c = *(const float4*)&egt[1 * Hn];
    float4 eg2c = *(const float4*)&egt[2 * Hn];
    float4 eg3c = *(const float4*)&egt[3 * Hn];

    // num/den for one k-group (no divide): 13 fast ops.
#define P1ND(EG, NUM, DEN)                                                    \
    {                                                                         \
        const float d0 = fmaf(cur.x, EG.x, 1.0f);                             \
        const float d1 = fmaf(cur.y, EG.y, 1.0f);                             \
        const float d2 = fmaf(cur.z, EG.z, 1.0f);                             \
        const float d3 = fmaf(cur.w, EG.w, 1.0f);                             \
        const float p0 = d0 * d2;                                             \
        const float p1 = d1 * d3;                                             \
        const float n0 = fmaf(w4c.x, d2, w4c.z * d0);                         \
        const float n1 = fmaf(w4c.y, d3, w4c.w * d1);                         \
        NUM = fmaf(n0, p1, n1 * p0);                                          \
        DEN = p0 * p1;                                                        \
    }

    float numA0, numA1, numA2, numA3;
    float denA0, denA1, denA2, denA3;

#pragma unroll 2
    for (int kk2 = 0; kk2 < 64; kk2 += 2) {
        // ---- half A (kk2): compute num/den, defer the divide ----
        {
            const int k4n = kk2 + 1;                 // <= 63
            const float4 w4n  = *(const float4*)&wa2[k4n * 4];
            const float4 eg0n = *(const float4*)&egt[0 * Hn + k4n * 4];
            const float4 eg1n = *(const float4*)&egt[1 * Hn + k4n * 4];
            const float4 eg2n = *(const float4*)&egt[2 * Hn + k4n * 4];
            const float4 eg3n = *(const float4*)&egt[3 * Hn + k4n * 4];

            const float4 cur = ep[kk2 * Sn + tid];

            P1ND(eg0c, numA0, denA0)
            P1ND(eg1c, numA1, denA1)
            P1ND(eg2c, numA2, denA2)
            P1ND(eg3c, numA3, denA3)

            w4c = w4n; eg0c = eg0n; eg1c = eg1n; eg2c = eg2n; eg3c = eg3n;
        }
        // ---- half B (kk2+1): compute, combine pairwise, single rcp ----
        {
            const int k4n = (kk2 + 2) & 63;
            const float4 w4n  = *(const float4*)&wa2[k4n * 4];
            const float4 eg0n = *(const float4*)&egt[0 * Hn + k4n * 4];
            const float4 eg1n = *(const float4*)&egt[1 * Hn + k4n * 4];
            const float4 eg2n = *(const float4*)&egt[2 * Hn + k4n * 4];
            const float4 eg3n = *(const float4*)&egt[3 * Hn + k4n * 4];

            const float4 cur = ep[(kk2 + 1) * Sn + tid];

            float nb, db;
            P1ND(eg0c, nb, db)
            acc0 = fmaf(fmaf(numA0, db, nb * denA0),
                        __builtin_amdgcn_rcpf(denA0 * db), acc0);
            P1ND(eg1c, nb, db)
            acc1 = fmaf(fmaf(numA1, db, nb * denA1),
                        __builtin_amdgcn_rcpf(denA1 * db), acc1);
            P1ND(eg2c, nb, db)
            acc2 = fmaf(fmaf(numA2, db, nb * denA2),
                        __builtin_amdgcn_rcpf(denA2 * db), acc2);
            P1ND(eg3c, nb, db)
            acc3 = fmaf(fmaf(numA3, db, nb * denA3),
                        __builtin_amdgcn_rcpf(denA3 * db), acc3);

            w4c = w4n; eg0c = eg0n; eg1c = eg1n; eg2c = eg2n; eg3c = eg3n;
        }
    }
#undef P1ND

    const float accv[4] = {acc0, acc1, acc2, acc3};

    // ---- softmax: every thread owns full k of its 4 rows ----
    float ex[4];
    const float k0 = cst[0];
#pragma unroll
    for (int r = 0; r < 4; r++) {
        const float e1  = __builtin_amdgcn_exp2f(fmaf(-L2E, accv[r], k0));
        const float sig = __builtin_amdgcn_rcpf(1.0f + e1);
        ex[r] = __builtin_amdgcn_exp2f(L2E * sig);   // sig in (0,1)
    }
    const int lane = tid & 63, wid = tid >> 6;       // wid 0..7
#pragma unroll
    for (int r = 0; r < 4; r++) {
        float v = ex[r];
#pragma unroll
        for (int off = 32; off >= 1; off >>= 1) v += __shfl_xor(v, off, 64);
        if (lane == 0) red[r * 8 + wid] = v;
    }
    __syncthreads();

#pragma unroll
    for (int r = 0; r < 4; r++) {
        float tot = 0.f;
#pragma unroll
        for (int j = 0; j < 8; j++) tot += red[r * 8 + j];
        const float a = ex[r] * __builtin_amdgcn_rcpf(tot);
        attn_l[r * Sn + tid] = a;
        out_attn[(b * Sn + t0 + r) * Sn + tid] = a;
    }
    __syncthreads();

    // ---- phase 2: out rows = attn @ h. 8 q-groups of 64 t' each ----
    const int c4 = tid & 63;
    const int q  = tid >> 6;                 // 0..7, wave-uniform

    const float* __restrict__ hb = hsrc + (b * Sn + q * 64) * Hn + c4 * 4;

    float4 a4[4];
#pragma unroll
    for (int r = 0; r < 4; r++) a4[r] = (float4){0.f, 0.f, 0.f, 0.f};

#pragma unroll 2
    for (int j4 = 0; j4 < 16; j4++) {
        float4 wv[4];
#pragma unroll
        for (int r = 0; r < 4; r++)
            wv[r] = *(const float4*)&attn_l[r * Sn + q * 64 + j4 * 4];  // bcast
#pragma unroll
        for (int i = 0; i < 4; i++) {
            const float4 hv = *(const float4*)&hb[(j4 * 4 + i) * Hn];
#pragma unroll
            for (int r = 0; r < 4; r++) {
                const float wr = ((const float*)&wv[r])[i];
                a4[r].x = fmaf(wr, hv.x, a4[r].x);
                a4[r].y = fmaf(wr, hv.y, a4[r].y);
                a4[r].z = fmaf(wr, hv.z, a4[r].z);
                a4[r].w = fmaf(wr, hv.w, a4[r].w);
            }
        }
    }

    // two-stage q reduction into dedicated part (no aliasing)
    if (q < 4) {
#pragma unroll
        for (int r = 0; r < 4; r++) part[(q * 4 + r) * 64 + c4] = a4[r];
    }
    __syncthreads();
    if (q >= 4) {
#pragma unroll
        for (int r = 0; r < 4; r++) {
            float4 p = part[((q - 4) * 4 + r) * 64 + c4];
            p.x += a4[r].x; p.y += a4[r].y; p.z += a4[r].z; p.w += a4[r].w;
            part[((q - 4) * 4 + r) * 64 + c4] = p;
        }
    }
    __syncthreads();

    // final: 512 threads = 256 cols x 2 row-pairs; sum the 4 q-partials
    {
        const int col = tid & 255;
        const int rb  = (tid >> 8) * 2;      // 0 or 2
        const float* pf = (const float*)part;
#pragma unroll
        for (int i = 0; i < 2; i++) {
            const int r = rb + i;
            float s = 0.f;
#pragma unroll
            for (int qq = 0; qq < 4; qq++)
                s += pf[((qq * 4 + r) * 64 + (col >> 2)) * 4 + (col & 3)];
            out[(b * Sn + t0 + r) * Hn + col] = s;
        }
    }
}

extern "C" void kernel_launch(void* const* d_in, const int* in_sizes, int n_in,
                              void* d_out, int out_size, void* d_ws, size_t ws_size,
                              hipStream_t stream) {
    const float* h   = (const float*)d_in[0];
    const float* Wt  = (const float*)d_in[1];
    const float* Wtp = (const float*)d_in[2];
    const float* bh  = (const float*)d_in[3];
    const float* Wa  = (const float*)d_in[4];
    const float* ba  = (const float*)d_in[5];

    float* out      = (float*)d_out;                 // (B,S,H) = 524288
    float* out_attn = out + Bn * Sn * Hn;            // (B,S,S) = 1048576

    float* ws   = (float*)d_ws;
    float* Egt  = ws;                                 // 524288 f
    float* Egp4 = ws + 524288;                        // 524288 f
    float* wa2  = ws + 1048576;                       // 256 f
    float* cst  = ws + 1048832;                       // 1 f

    gemm_kernel<<<dim3(512), dim3(512), 0, stream>>>(
        h, Wt, Wtp, Wa, ba, bh, Egt, Egp4, wa2, cst);
    attn_kernel<<<dim3(Bn * (Sn / 4)), dim3(512), 0, stream>>>(
        h, Egt, Egp4, wa2, cst, out, out_attn);
}

// Round 11
// 109.263 us; speedup vs baseline: 1.0676x; 1.0676x over previous
//
#include <hip/hip_runtime.h>

// Problem constants: B=4, S=512, H=256
#define Bn 4
#define Sn 512
#define Hn 256

#define CC   2.8853900817779268f   // 2*log2(e)
#define L2E  1.4426950408889634f

typedef __attribute__((ext_vector_type(4))) float f32x4;
typedef __attribute__((ext_vector_type(8))) short short8;

__device__ __forceinline__ unsigned short bf16rn(float f) {
    unsigned int u = __float_as_uint(f);
    u += 0x7fffu + ((u >> 16) & 1u);
    return (unsigned short)(u >> 16);
}
__device__ __forceinline__ float bf16tof(unsigned short b) {
    return __uint_as_float(((unsigned int)b) << 16);
}

// ---------------------------------------------------------------------------
// gemm (kept verbatim): R16 structure + (0,2,1,3) within-group layout
// permutation in Egt/Egp4/wa2 (proven bit-identical at the consumer).
// ---------------------------------------------------------------------------
__global__ __launch_bounds__(512, 4) void gemm_kernel(
    const float* __restrict__ h,  const float* __restrict__ Wt,
    const float* __restrict__ Wp, const float* __restrict__ Wa,
    const float* __restrict__ ba, const float* __restrict__ bh,
    float* __restrict__ Egt, float* __restrict__ Egp4,
    float* __restrict__ wa2, float* __restrict__ cst)
{
    // A1@0 A2@8704 (32x136 shorts) B1@17408 B2@34816 (64x136 shorts)
    // tile@52224 (32x68 f32; reused as ct) red4@60928
    __shared__ char lds[60944];
    unsigned short* A1 = (unsigned short*)lds;
    unsigned short* A2 = (unsigned short*)(lds + 8704);
    unsigned short* B1 = (unsigned short*)(lds + 17408);
    unsigned short* B2 = (unsigned short*)(lds + 34816);
    float* tile = (float*)(lds + 52224);
    float* red4 = (float*)(lds + 60928);

    const int tid = threadIdx.x;            // 0..511
    const int mb  = blockIdx.x >> 3;        // 0..63 (32-row m-tiles)
    const int nb  = blockIdx.x & 7;
    const int m0  = mb * 32;
    const bool isT = (nb < 4);
    const int n0  = (isT ? nb : nb - 4) * 64;
    const float* __restrict__ W = isT ? Wt : Wp;

    if (blockIdx.x == 0) {
        if (tid < 256) {
            float wv = Wa[tid];
#pragma unroll
            for (int off = 32; off >= 1; off >>= 1) wv += __shfl_xor(wv, off, 64);
            if ((tid & 63) == 0) red4[tid >> 6] = wv;
        }
        __syncthreads();
        if (tid < 256) {
            // permuted within group of 4: mem pos p holds orig j = {0,2,1,3}[p]
            const int p   = tid & 3;
            const int src = (tid & ~3) | (((p << 1) | (p >> 1)) & 3);
            wa2[tid] = -2.0f * Wa[src];
        }
        if (tid == 0)
            cst[0] = -L2E * ((red4[0] + red4[1] + red4[2] + red4[3]) + ba[0]);
    }

    const int w    = tid >> 6;              // 0..7
    const int w2   = w & 3;                 // n-quadrant
    const int mh   = w >> 2;                // m-half
    const int lane = tid & 63;
    const int quad = lane >> 4;
    const int l15  = lane & 15;

    f32x4 acc = (f32x4){0.f, 0.f, 0.f, 0.f};

    for (int kh2 = 0; kh2 < 2; kh2++) {
        const int K0 = kh2 << 7;
        __syncthreads();

        {
            const int row = tid >> 4;
            const int seg = (tid & 15) * 8;
            const float* __restrict__ src = h + (m0 + row) * Hn + K0 + seg;
            unsigned int* d1 = (unsigned int*)A1 + row * 68 + (seg >> 1);
            unsigned int* d2 = (unsigned int*)A2 + row * 68 + (seg >> 1);
#pragma unroll
            for (int i = 0; i < 2; i++) {
                const float4 v = ((const float4*)src)[i];
                const float f[4] = {v.x, v.y, v.z, v.w};
                unsigned short b1[4], b2[4];
#pragma unroll
                for (int j = 0; j < 4; j++) {
                    b1[j] = bf16rn(f[j]);
                    b2[j] = bf16rn(f[j] - bf16tof(b1[j]));
                }
                d1[2 * i]     = (unsigned)b1[0] | ((unsigned)b1[1] << 16);
                d1[2 * i + 1] = (unsigned)b1[2] | ((unsigned)b1[3] << 16);
                d2[2 * i]     = (unsigned)b2[0] | ((unsigned)b2[1] << 16);
                d2[2 * i + 1] = (unsigned)b2[2] | ((unsigned)b2[3] << 16);
            }
        }

        for (int kt = 0; kt < 4; kt++) {
            const int koff = K0 + kt * 32;
            if (kt) __syncthreads();
            {
                const int kr = tid >> 4;
                const int nq = tid & 15;
                *(float4*)&tile[kr * 68 + nq * 4] =
                    *(const float4*)&W[(koff + kr) * Hn + n0 + nq * 4];
            }
            __syncthreads();
            {
                const int n  = tid >> 3;
                const int p0 = (tid & 7) * 2;
                const float f0 = tile[(2 * p0    ) * 68 + n];
                const float f1 = tile[(2 * p0 + 1) * 68 + n];
                const float f2 = tile[(2 * p0 + 2) * 68 + n];
                const float f3 = tile[(2 * p0 + 3) * 68 + n];
                const unsigned short a0 = bf16rn(f0), a1 = bf16rn(f1);
                const unsigned short a2 = bf16rn(f2), a3 = bf16rn(f3);
                const unsigned short c0 = bf16rn(f0 - bf16tof(a0));
                const unsigned short c1 = bf16rn(f1 - bf16tof(a1));
                const unsigned short c2 = bf16rn(f2 - bf16tof(a2));
                const unsigned short c3 = bf16rn(f3 - bf16tof(a3));
                unsigned int* o1 = (unsigned int*)B1 + n * 68 + kt * 16 + p0;
                unsigned int* o2 = (unsigned int*)B2 + n * 68 + kt * 16 + p0;
                o1[0] = (unsigned)a0 | ((unsigned)a1 << 16);
                o1[1] = (unsigned)a2 | ((unsigned)a3 << 16);
                o2[0] = (unsigned)c0 | ((unsigned)c1 << 16);
                o2[1] = (unsigned)c2 | ((unsigned)c3 << 16);
            }
        }
        __syncthreads();

#pragma unroll
        for (int ks = 0; ks < 128; ks += 32) {
            const int bof = (w2 * 16 + l15) * 136 + ks + quad * 8;
            const short8 b1 = *(const short8*)(B1 + bof);
            const short8 b2 = *(const short8*)(B2 + bof);
            const int aof = (mh * 16 + l15) * 136 + ks + quad * 8;
            const short8 a1 = *(const short8*)(A1 + aof);
            const short8 a2 = *(const short8*)(A2 + aof);
            acc = __builtin_amdgcn_mfma_f32_16x16x32_bf16(a1, b1, acc, 0, 0, 0);
            acc = __builtin_amdgcn_mfma_f32_16x16x32_bf16(a1, b2, acc, 0, 0, 0);
            acc = __builtin_amdgcn_mfma_f32_16x16x32_bf16(a2, b1, acc, 0, 0, 0);
        }
    }

    float* ct = tile;
#pragma unroll
    for (int r = 0; r < 4; r++)
        ct[(mh * 16 + quad * 4 + r) * 68 + w2 * 16 + l15] = acc[r];
    __syncthreads();

    const int b  = m0 >> 9;
    const int s0 = m0 & 511;
    if (isT) {
        const int n0g = nb * 64;
        const int mr = tid >> 4, nq = tid & 15;
        const float4 c  = *(const float4*)&ct[mr * 68 + nq * 4];
        const float4 bv = *(const float4*)&bh[n0g + nq * 4];
        // permuted store: mem (x,y,z,w) <- orig (0,2,1,3)
        float4 o;
        o.x = __builtin_amdgcn_exp2f((c.x + bv.x) * CC);
        o.y = __builtin_amdgcn_exp2f((c.z + bv.z) * CC);
        o.z = __builtin_amdgcn_exp2f((c.y + bv.y) * CC);
        o.w = __builtin_amdgcn_exp2f((c.w + bv.w) * CC);
        *(float4*)&Egt[(m0 + mr) * Hn + n0g + nq * 4] = o;
    } else {
        const int kq0 = (nb - 4) * 16;
        const int mr = tid & 31, nq = tid >> 5;
        const float4 c = *(const float4*)&ct[mr * 68 + nq * 4];
        // permuted store: mem (x,y,z,w) <- orig (0,2,1,3)
        float4 o;
        o.x = __builtin_amdgcn_exp2f(c.x * CC);
        o.y = __builtin_amdgcn_exp2f(c.z * CC);
        o.z = __builtin_amdgcn_exp2f(c.y * CC);
        o.w = __builtin_amdgcn_exp2f(c.w * CC);
        *(float4*)&Egp4[b * 131072 + (kq0 + nq) * 2048 + (s0 + mr) * 4] = o;
    }
}

// ---------------------------------------------------------------------------
// attn R26 = R23 verbatim (best measured: 40.6us attn, 108.04us total).
// R25's pairwise rcp fusion spilled to scratch under the (512,8) register
// budget (WRITE_SIZE 6144->10240 KB) and regressed 40.6->49.0; reverted.
// Lever ledger for this structure (all falsified): VMEM SW-pipeline (R17),
// sync-shrink (R18/R20), occupancy x2 (R22==R23), pk-f32 (R21), SMEM->LDS
// (R24), rcp fusion (R25). One win: de-arrayed SGPR operands (R22, -4us).
// Busy 20.7us vs 16us algorithmic floor; residual ~20us idle is issue/
// scheduling structure unreachable from HIP source.
// ---------------------------------------------------------------------------
__global__ __launch_bounds__(512, 8) void attn_kernel(
    const float* __restrict__ hsrc, const float* __restrict__ Egt,
    const float* __restrict__ Egp4, const float* __restrict__ wa2,
    const float* __restrict__ cst,
    float* __restrict__ out, float* __restrict__ out_attn)
{
    __shared__ float  attn_l[4 * 512];     // 8 KB
    __shared__ float  red[32];
    __shared__ float4 part[4 * 4 * 64];    // 16 KB, two-stage q reduction

    const int tid = threadIdx.x;           // 0..511
    const int b   = blockIdx.x & 3;
    const int t0  = (blockIdx.x >> 2) << 2;

    const float* __restrict__ egt = Egt + (b * Sn + t0) * Hn;   // block-uniform
    const float4* __restrict__ ep = (const float4*)(Egp4 + b * (Hn * Sn));

    float acc0 = 0.f, acc1 = 0.f, acc2 = 0.f, acc3 = 0.f;

    float4 w4c  = *(const float4*)&wa2[0];
    float4 eg0c = *(const float4*)&egt[0 * Hn];
    float4 eg1c = *(const float4*)&egt[1 * Hn];
    float4 eg2c = *(const float4*)&egt[2 * Hn];
    float4 eg3c = *(const float4*)&egt[3 * Hn];

    // Exact R22 body: eg/w4 fields referenced directly (SGPR operand inline).
#define P1ROW(EG, ACC)                                                        \
    {                                                                         \
        const float d0 = fmaf(cur.x, EG.x, 1.0f);                             \
        const float d1 = fmaf(cur.y, EG.y, 1.0f);                             \
        const float d2 = fmaf(cur.z, EG.z, 1.0f);                             \
        const float d3 = fmaf(cur.w, EG.w, 1.0f);                             \
        const float p0 = d0 * d2;                                             \
        const float p1 = d1 * d3;                                             \
        const float n0 = fmaf(w4c.x, d2, w4c.z * d0);                         \
        const float n1 = fmaf(w4c.y, d3, w4c.w * d1);                         \
        const float num = fmaf(n0, p1, n1 * p0);                              \
        ACC = fmaf(num, __builtin_amdgcn_rcpf(p0 * p1), ACC);                 \
    }

#pragma unroll 2
    for (int kk = 0; kk < 64; kk++) {
        const int k4n = (kk + 1) & 63;
        const float4 w4n  = *(const float4*)&wa2[k4n * 4];
        const float4 eg0n = *(const float4*)&egt[0 * Hn + k4n * 4];
        const float4 eg1n = *(const float4*)&egt[1 * Hn + k4n * 4];
        const float4 eg2n = *(const float4*)&egt[2 * Hn + k4n * 4];
        const float4 eg3n = *(const float4*)&egt[3 * Hn + k4n * 4];

        const float4 cur = ep[kk * Sn + tid];   // coalesced vector load

        P1ROW(eg0c, acc0)
        P1ROW(eg1c, acc1)
        P1ROW(eg2c, acc2)
        P1ROW(eg3c, acc3)

        w4c = w4n; eg0c = eg0n; eg1c = eg1n; eg2c = eg2n; eg3c = eg3n;
    }
#undef P1ROW

    const float accv[4] = {acc0, acc1, acc2, acc3};

    // ---- softmax: every thread owns full k of its 4 rows ----
    float ex[4];
    const float k0 = cst[0];
#pragma unroll
    for (int r = 0; r < 4; r++) {
        const float e1  = __builtin_amdgcn_exp2f(fmaf(-L2E, accv[r], k0));
        const float sig = __builtin_amdgcn_rcpf(1.0f + e1);
        ex[r] = __builtin_amdgcn_exp2f(L2E * sig);   // sig in (0,1)
    }
    const int lane = tid & 63, wid = tid >> 6;       // wid 0..7
#pragma unroll
    for (int r = 0; r < 4; r++) {
        float v = ex[r];
#pragma unroll
        for (int off = 32; off >= 1; off >>= 1) v += __shfl_xor(v, off, 64);
        if (lane == 0) red[r * 8 + wid] = v;
    }
    __syncthreads();

#pragma unroll
    for (int r = 0; r < 4; r++) {
        float tot = 0.f;
#pragma unroll
        for (int j = 0; j < 8; j++) tot += red[r * 8 + j];
        const float a = ex[r] * __builtin_amdgcn_rcpf(tot);
        attn_l[r * Sn + tid] = a;
        out_attn[(b * Sn + t0 + r) * Sn + tid] = a;
    }
    __syncthreads();

    // ---- phase 2: out rows = attn @ h. 8 q-groups of 64 t' each ----
    const int c4 = tid & 63;
    const int q  = tid >> 6;                 // 0..7, wave-uniform

    const float* __restrict__ hb = hsrc + (b * Sn + q * 64) * Hn + c4 * 4;

    float4 a4[4];
#pragma unroll
    for (int r = 0; r < 4; r++) a4[r] = (float4){0.f, 0.f, 0.f, 0.f};

#pragma unroll 2
    for (int j4 = 0; j4 < 16; j4++) {
        float4 wv[4];
#pragma unroll
        for (int r = 0; r < 4; r++)
            wv[r] = *(const float4*)&attn_l[r * Sn + q * 64 + j4 * 4];  // bcast
#pragma unroll
        for (int i = 0; i < 4; i++) {
            const float4 hv = *(const float4*)&hb[(j4 * 4 + i) * Hn];
#pragma unroll
            for (int r = 0; r < 4; r++) {
                const float wr = ((const float*)&wv[r])[i];
                a4[r].x = fmaf(wr, hv.x, a4[r].x);
                a4[r].y = fmaf(wr, hv.y, a4[r].y);
                a4[r].z = fmaf(wr, hv.z, a4[r].z);
                a4[r].w = fmaf(wr, hv.w, a4[r].w);
            }
        }
    }

    // two-stage q reduction into dedicated part (no aliasing)
    if (q < 4) {
#pragma unroll
        for (int r = 0; r < 4; r++) part[(q * 4 + r) * 64 + c4] = a4[r];
    }
    __syncthreads();
    if (q >= 4) {
#pragma unroll
        for (int r = 0; r < 4; r++) {
            float4 p = part[((q - 4) * 4 + r) * 64 + c4];
            p.x += a4[r].x; p.y += a4[r].y; p.z += a4[r].z; p.w += a4[r].w;
            part[((q - 4) * 4 + r) * 64 + c4] = p;
        }
    }
    __syncthreads();

    // final: 512 threads = 256 cols x 2 row-pairs; sum the 4 q-partials
    {
        const int col = tid & 255;
        const int rb  = (tid >> 8) * 2;      // 0 or 2
        const float* pf = (const float*)part;
#pragma unroll
        for (int i = 0; i < 2; i++) {
            const int r = rb + i;
            float s = 0.f;
#pragma unroll
            for (int qq = 0; qq < 4; qq++)
                s += pf[((qq * 4 + r) * 64 + (col >> 2)) * 4 + (col & 3)];
            out[(b * Sn + t0 + r) * Hn + col] = s;
        }
    }
}

extern "C" void kernel_launch(void* const* d_in, const int* in_sizes, int n_in,
                              void* d_out, int out_size, void* d_ws, size_t ws_size,
                              hipStream_t stream) {
    const float* h   = (const float*)d_in[0];
    const float* Wt  = (const float*)d_in[1];
    const float* Wtp = (const float*)d_in[2];
    const float* bh  = (const float*)d_in[3];
    const float* Wa  = (const float*)d_in[4];
    const float* ba  = (const float*)d_in[5];

    float* out      = (float*)d_out;                 // (B,S,H) = 524288
    float* out_attn = out + Bn * Sn * Hn;            // (B,S,S) = 1048576

    float* ws   = (float*)d_ws;
    float* Egt  = ws;                                 // 524288 f
    float* Egp4 = ws + 524288;                        // 524288 f
    float* wa2  = ws + 1048576;                       // 256 f
    float* cst  = ws + 1048832;                       // 1 f

    gemm_kernel<<<dim3(512), dim3(512), 0, stream>>>(
        h, Wt, Wtp, Wa, ba, bh, Egt, Egp4, wa2, cst);
    attn_kernel<<<dim3(Bn * (Sn / 4)), dim3(512), 0, stream>>>(
        h, Egt, Egp4, wa2, cst, out, out_attn);
}